// Round 1
// baseline (250.952 us; speedup 1.0000x reference)
//
#include <hip/hip_runtime.h>

// Problem constants
#define LDIM 16384
#define KDIM 288
#define ODIM 64
#define BDIM 8

typedef float f32x4 __attribute__((ext_vector_type(4)));

// ---------------------------------------------------------------------------
// Single-kernel fp32 version.
//
// Rationale vs the previous bf16-MFMA kernel:
//  * compute is tiny (2.4 G lane-FMAs -> ~31 us at the 157 TF fp32 vector
//    ceiling), so MFMA buys nothing; the old kernel was structure-bound at
//    230 us AND carried an unexplained ~0.043 absmax error (100x what honest
//    bf16 rounding predicts) sitting exactly on the harness threshold.
//  * full fp32 FMA path -> absmax ~1e-4, immune to threshold-sitting and to
//    any re-poisoned-input data dependence.
//  * plain reg-staged LDS (ds_write + two __syncthreads per chunk) replaces
//    the async global_load_lds double-buffer pipeline -- simple, obviously
//    race-free ordering.
//
// Tiling: block = 256 threads (4 waves) owns 128 l x 64 o.
//   thread t: to = t&7 (8 o's: to*8..), tl = t>>3 (4 l's: tl*4..)
//   K is processed in 9 chunks of 32. LDS: xs[32][128] 16KB + ws[32][64] 8KB.
//   Next chunk's global loads are issued before the compute phase so ~900 cy
//   of HBM latency hides under ~2300 cy of FMAs; 4 blocks/CU give TLP on top.
// ---------------------------------------------------------------------------
__global__ __launch_bounds__(256, 4) void gauss_fp32(
    const float* __restrict__ x, const float* __restrict__ w,
    const float* __restrict__ bias, const float* __restrict__ gammap,
    float* __restrict__ out) {
  __shared__ float xs[32 * 128];  // x chunk: [k][l], also cw scratch pre-loop
  __shared__ float ws[32 * 64];   // w chunk: [k][o]
  __shared__ float cwb[64];       // -gamma * sum_k w[k][o]^2

  const int t = threadIdx.x;
  const int tl = t >> 3;  // 0..31 : l-tile index AND staging row
  const int to = t & 7;   // 0..7  : o-tile index

  const long g0 = (long)blockIdx.x * 128;  // global row (b*L + l)
  const int bidx = (int)(g0 >> 14);        // L = 16384
  const int l0 = (int)(g0 & (LDIM - 1));
  const float* xb = x + (long)bidx * ((long)KDIM * LDIM) + l0;

  const float gamma = gammap[0];

  // ---- issue chunk-0 staging loads first (latency hides under cw loop)
  // x: thread covers k-row tl, l-cols to*16 .. to*16+15 of the chunk
  // w: thread covers k-row tl, o-cols to*8 .. to*8+7
  const float* gpx = xb + (long)tl * LDIM + to * 16;
  const float* gpw = w + tl * 64 + to * 8;  // wv[k][o] = w_flat[k*64+o]
  f32x4 xa[4], wa[2];
#pragma unroll
  for (int v = 0; v < 4; ++v) xa[v] = *(const f32x4*)(gpx + v * 4);
#pragma unroll
  for (int v = 0; v < 2; ++v) wa[v] = *(const f32x4*)(gpw + v * 4);

  // ---- per-block cw[o] = -gamma * sum_k w[k][o]^2  (xs[0..255] as scratch)
  {
    const int seg = t >> 6, o = t & 63;
    float s = 0.f;
#pragma unroll 8
    for (int k = seg * 72; k < seg * 72 + 72; ++k) {
      float v = w[k * 64 + o];
      s = fmaf(v, v, s);
    }
    xs[t] = s;
    __syncthreads();
    if (t < 64)
      cwb[t] = -gamma * (xs[t] + xs[t + 64] + xs[t + 128] + xs[t + 192]);
    // no barrier needed here: the first loop iteration's barrier orders the
    // xs scratch reads above against the ds_writes below for ALL threads.
  }

  float acc[4][8];
#pragma unroll
  for (int i = 0; i < 4; ++i)
#pragma unroll
    for (int j = 0; j < 8; ++j) acc[i][j] = 0.f;
  float x2a[4] = {0.f, 0.f, 0.f, 0.f};  // sum_k x[l]^2, exact fp32

#pragma unroll 1
  for (int kc = 0; kc < 9; ++kc) {
    __syncthreads();  // LDS free (previous chunk consumed / scratch read)
#pragma unroll
    for (int v = 0; v < 4; ++v) *(f32x4*)&xs[t * 16 + v * 4] = xa[v];
#pragma unroll
    for (int v = 0; v < 2; ++v) *(f32x4*)&ws[t * 8 + v * 4] = wa[v];
    __syncthreads();  // LDS ready

    // issue next chunk's global loads now; they complete under the FMAs
    if (kc < 8) {
      const float* nx = gpx + (long)(kc + 1) * 32 * LDIM;
      const float* nw = gpw + (kc + 1) * 32 * 64;
#pragma unroll
      for (int v = 0; v < 4; ++v) xa[v] = *(const f32x4*)(nx + v * 4);
#pragma unroll
      for (int v = 0; v < 2; ++v) wa[v] = *(const f32x4*)(nw + v * 4);
    }

    // compute: 32 k-steps, 36 FMAs + 3 ds_read_b128 each.
    // x-read: 8 distinct 16B addrs/wave (bank-clean, 8-way broadcast);
    // w-read: 2-way bank alias (free).
#pragma unroll 8
    for (int k = 0; k < 32; ++k) {
      f32x4 x4 = *(const f32x4*)&xs[k * 128 + tl * 4];
      f32x4 w8a = *(const f32x4*)&ws[k * 64 + to * 8];
      f32x4 w8b = *(const f32x4*)&ws[k * 64 + to * 8 + 4];
#pragma unroll
      for (int i = 0; i < 4; ++i) x2a[i] = fmaf(x4[i], x4[i], x2a[i]);
#pragma unroll
      for (int i = 0; i < 4; ++i) {
#pragma unroll
        for (int j = 0; j < 4; ++j) {
          acc[i][j] = fmaf(x4[i], w8a[j], acc[i][j]);
          acc[i][j + 4] = fmaf(x4[i], w8b[j], acc[i][j + 4]);
        }
      }
    }
  }

  // ---- epilogue: e = -gamma*(x2 + w2 - 2*xw); out = exp(e) + bias
  const float coef = 2.f * gamma;
  const f32x4 cwv_a = *(const f32x4*)&cwb[to * 8];
  const f32x4 cwv_b = *(const f32x4*)&cwb[to * 8 + 4];
  const f32x4 bv_a = *(const f32x4*)&bias[to * 8];
  const f32x4 bv_b = *(const f32x4*)&bias[to * 8 + 4];

  float* outw = out + (g0 + tl * 4) * 64 + to * 8;
#pragma unroll
  for (int i = 0; i < 4; ++i) {
    const float cx = -gamma * x2a[i];
    f32x4 r0, r1;
#pragma unroll
    for (int j = 0; j < 4; ++j) {
      r0[j] = __expf(fmaf(coef, acc[i][j], cx + cwv_a[j])) + bv_a[j];
      r1[j] = __expf(fmaf(coef, acc[i][j + 4], cx + cwv_b[j])) + bv_b[j];
    }
    *(f32x4*)(outw + i * 64) = r0;
    *(f32x4*)(outw + i * 64 + 4) = r1;
  }
}

extern "C" void kernel_launch(void* const* d_in, const int* in_sizes, int n_in,
                              void* d_out, int out_size, void* d_ws, size_t ws_size,
                              hipStream_t stream) {
  const float* x = (const float*)d_in[0];      // [8, 288, 16384]
  const float* w = (const float*)d_in[1];      // [64, 32, 3, 3] -> flat 18432
  const float* b = (const float*)d_in[2];      // [64]
  const float* gamma = (const float*)d_in[3];  // scalar
  float* out = (float*)d_out;                  // [8, 16384, 64]

  (void)d_ws; (void)ws_size;
  gauss_fp32<<<1024, 256, 0, stream>>>(x, w, b, gamma, out);
}

// Round 2
// 241.781 us; speedup vs baseline: 1.0379x; 1.0379x over previous
//
#include <hip/hip_runtime.h>

// Problem constants
#define LDIM 16384
#define KDIM 288
#define ODIM 64
#define BDIM 8

typedef float f32x4 __attribute__((ext_vector_type(4)));

// ---------------------------------------------------------------------------
// fp32, LDS-throughput-optimized version.
//
// Round-1 diagnosis: kernel was LDS-read-bound, not VALU-bound (VALUBusy 44%,
// HBM 16%). 4lx8o microtile = 0.75 FMA/LDS-byte -> 3.6 GB LDS traffic ~ 69 us
// on the one-per-CU LDS pipe. This version:
//   * 8l x 8o per-thread microtile (64 acc regs) -> 1.0 FMA/LDS-byte (2.4 GB)
//   * global_load_lds staging (wave-linear 1KB rows, no ds_writes, no VGPR
//     round trip), double-buffered, ONE barrier per k-chunk
//   * block 256 threads = 256 l x 64 o; grid 512; k-chunk 32 (9 chunks)
//   * LDS 2x32KB (x) + 2x8KB (w) = 80 KB -> 2 blocks/CU
//   * cw reduction scratch aliases w-buffer 1 (sequenced by barriers before
//     STAGE(1) overwrites it); cw/bias then live in registers
// ---------------------------------------------------------------------------
__global__ __launch_bounds__(256, 2) void gauss_fp32(
    const float* __restrict__ x, const float* __restrict__ w,
    const float* __restrict__ bias, const float* __restrict__ gammap,
    float* __restrict__ out) {
  // [2][32][256] x-chunks, then [2][32][64] w-chunks. 80 KB total.
  __shared__ float lds[2 * 8192 + 2 * 2048];
  float* const xs0 = lds;
  float* const ws0 = lds + 16384;
  float* const red = ws0 + 2048;  // aliases w buffer 1 (safe: see sequencing)

  const int t = threadIdx.x;
  const int lane = t & 63;
  const int wvid = t >> 6;
  const int tl = t >> 3;  // 0..31 : l-block = tl*8
  const int to = t & 7;   // 0..7  : o-block = to*8

  const long g0 = (long)blockIdx.x * 256;  // global row (b*L + l); 256 | 16384
  const int bidx = (int)(g0 >> 14);
  const int l0 = (int)(g0 & (LDIM - 1));
  const float* xb = x + (long)bidx * ((long)KDIM * LDIM) + l0;

  // One global_load_lds instr stages one 1 KB row: global addr is per-lane
  // (row base + lane*16B), LDS dest is wave-uniform base (+ lane*16 in HW).
#define STAGE(KC, BUF)                                                         \
  {                                                                            \
    const float* xsrc = xb + (long)((KC) * 32) * LDIM + lane * 4;              \
    float* xdst = xs0 + (BUF) * 8192;                                          \
    _Pragma("unroll") for (int i = 0; i < 8; ++i) {                            \
      int r = wvid * 8 + i;                                                    \
      __builtin_amdgcn_global_load_lds(                                        \
          (const __attribute__((address_space(1))) unsigned int*)(void*)       \
              (xsrc + (long)r * LDIM),                                         \
          (__attribute__((address_space(3))) unsigned int*)(void*)             \
              (xdst + r * 256),                                                \
          16, 0, 0);                                                           \
    }                                                                          \
    const float* wsrc = w + (KC) * 2048 + lane * 4;                            \
    float* wdst = ws0 + (BUF) * 2048;                                          \
    _Pragma("unroll") for (int j = 0; j < 2; ++j) {                            \
      int s = wvid * 2 + j;                                                    \
      __builtin_amdgcn_global_load_lds(                                        \
          (const __attribute__((address_space(1))) unsigned int*)(void*)       \
              (wsrc + s * 256),                                                \
          (__attribute__((address_space(3))) unsigned int*)(void*)             \
              (wdst + s * 256),                                                \
          16, 0, 0);                                                           \
    }                                                                          \
  }

  // ---- issue chunk-0 staging first; cw partial sums hide under it
  STAGE(0, 0)
  const float gamma = gammap[0];
  {
    const int seg = t >> 6, o = t & 63;
    float s = 0.f;
#pragma unroll 8
    for (int k = seg * 72; k < seg * 72 + 72; ++k) {
      float v = w[k * 64 + o];  // lanes cover o=0..63 -> coalesced 256 B
      s = fmaf(v, v, s);
    }
    red[t] = s;
  }
  __syncthreads();  // red visible; implicit vmcnt(0) also drains STAGE(0)

  float cwv[8], bv[8];
#pragma unroll
  for (int j = 0; j < 8; ++j) {
    int o = to * 8 + j;
    cwv[j] = -gamma * (red[o] + red[o + 64] + red[o + 128] + red[o + 192]);
    bv[j] = bias[o];
  }
  __syncthreads();  // all red reads done before STAGE(1) overwrites it
  STAGE(1, 1)

  float acc[8][8];
#pragma unroll
  for (int i = 0; i < 8; ++i)
#pragma unroll
    for (int j = 0; j < 8; ++j) acc[i][j] = 0.f;
  float x2a[8] = {0.f, 0.f, 0.f, 0.f, 0.f, 0.f, 0.f, 0.f};

  // Main loop: iteration kc computes from buf (kc&1), staged by STAGE(kc),
  // drained by the barrier at the end of iteration kc-1 (or pre-loop).
#pragma unroll 1
  for (int kc = 0; kc < 9; ++kc) {
    const float* xp = xs0 + (kc & 1) * 8192;
    const float* wp = ws0 + (kc & 1) * 2048;
#pragma unroll 4
    for (int k = 0; k < 32; ++k) {
      f32x4 xa0 = *(const f32x4*)(xp + k * 256 + tl * 8);
      f32x4 xa1 = *(const f32x4*)(xp + k * 256 + tl * 8 + 4);
      f32x4 wa0 = *(const f32x4*)(wp + k * 64 + to * 8);
      f32x4 wa1 = *(const f32x4*)(wp + k * 64 + to * 8 + 4);
      float xv[8];
#pragma unroll
      for (int i = 0; i < 4; ++i) { xv[i] = xa0[i]; xv[i + 4] = xa1[i]; }
#pragma unroll
      for (int i = 0; i < 8; ++i) x2a[i] = fmaf(xv[i], xv[i], x2a[i]);
#pragma unroll
      for (int i = 0; i < 8; ++i) {
#pragma unroll
        for (int j = 0; j < 4; ++j) {
          acc[i][j] = fmaf(xv[i], wa0[j], acc[i][j]);
          acc[i][j + 4] = fmaf(xv[i], wa1[j], acc[i][j + 4]);
        }
      }
    }
    __syncthreads();  // reads of buf(kc&1) done; drains STAGE(kc+1)
    if (kc < 7) STAGE(kc + 2, kc & 1)
  }

  // ---- epilogue: e = -gamma*(x2 + w2 - 2*xw); out = exp(e) + bias
  const float coef = 2.f * gamma;
  float* outw = out + (g0 + (long)tl * 8) * 64 + to * 8;
#pragma unroll
  for (int i = 0; i < 8; ++i) {
    const float cx = -gamma * x2a[i];
    f32x4 r0, r1;
#pragma unroll
    for (int j = 0; j < 4; ++j) {
      r0[j] = __expf(fmaf(coef, acc[i][j], cx + cwv[j])) + bv[j];
      r1[j] = __expf(fmaf(coef, acc[i][j + 4], cx + cwv[j + 4])) + bv[j + 4];
    }
    *(f32x4*)(outw + i * 64) = r0;
    *(f32x4*)(outw + i * 64 + 4) = r1;
  }
#undef STAGE
}

extern "C" void kernel_launch(void* const* d_in, const int* in_sizes, int n_in,
                              void* d_out, int out_size, void* d_ws, size_t ws_size,
                              hipStream_t stream) {
  const float* x = (const float*)d_in[0];      // [8, 288, 16384]
  const float* w = (const float*)d_in[1];      // [64, 32, 3, 3] -> flat 18432
  const float* b = (const float*)d_in[2];      // [64]
  const float* gamma = (const float*)d_in[3];  // scalar
  float* out = (float*)d_out;                  // [8, 16384, 64]

  (void)d_ws; (void)ws_size;
  gauss_fp32<<<512, 256, 0, stream>>>(x, w, b, gamma, out);
}